// Round 5
// baseline (208061.108 us; speedup 1.0000x reference)
//
#include <hip/hip_runtime.h>

#define Bq 32
#define Sq 2048
#define Iq 128
#define Hq 512
#define Oq 128
#define NWG 64
#define NT 512
#define SS 260  // LDS row stride (floats)

__device__ __forceinline__ float sigmoidf_(float v) {
    return 1.0f / (1.0f + __expf(-v));
}

// Relaxed agent-scope (LLC-coherent) access — no cache-maintenance fences.
__device__ __forceinline__ float ld_coh(const float* p) {
    return __hip_atomic_load(p, __ATOMIC_RELAXED, __HIP_MEMORY_SCOPE_AGENT);
}
__device__ __forceinline__ void st_coh(float* p, float v) {
    __hip_atomic_store(p, v, __ATOMIC_RELAXED, __HIP_MEMORY_SCOPE_AGENT);
}
__device__ __forceinline__ int ld_cohi(const int* p) {
    return __hip_atomic_load(p, __ATOMIC_RELAXED, __HIP_MEMORY_SCOPE_AGENT);
}
__device__ __forceinline__ void st_cohi(int* p, int v) {
    __hip_atomic_store(p, v, __ATOMIC_RELAXED, __HIP_MEMORY_SCOPE_AGENT);
}

// Decentralized flag barrier: 64 WGs, flag[w] on its OWN cache line (stride
// 16 dwords). Arrival = 1 relaxed store; every WG's wave 0 scans all 64
// flags itself (no master/publish hop). Monotone generations, no reset.
__device__ __forceinline__ void flagbar(int* flags, int ep) {
    asm volatile("s_waitcnt vmcnt(0) lgkmcnt(0)" ::: "memory");
    __syncthreads();  // all waves' data stores drained before arrival
    if (threadIdx.x == 0) st_cohi(flags + (blockIdx.x << 4), ep);
    if (threadIdx.x < 64) {
        for (;;) {
            int f = ld_cohi(flags + (threadIdx.x << 4));
            if (__all(f >= ep)) break;
            __builtin_amdgcn_s_sleep(4);
        }
    }
    __syncthreads();
}

// Stage 32 x 256 chunk of mutable state (coherent loads) into sst[b][k].
__device__ __forceinline__ void stage256(float* sst, const float* g, int k0) {
    __syncthreads();
    float4 v[4];
#pragma unroll
    for (int u = 0; u < 4; ++u) {
        int i = threadIdx.x + u * NT;
        int b = i & 31, k4 = i >> 5;
        const float* p = g + b * Hq + k0 + (k4 << 2);
        v[u].x = ld_coh(p);
        v[u].y = ld_coh(p + 1);
        v[u].z = ld_coh(p + 2);
        v[u].w = ld_coh(p + 3);
    }
#pragma unroll
    for (int u = 0; u < 4; ++u) {
        int i = threadIdx.x + u * NT;
        int b = i & 31, k4 = i >> 5;
        *(float4*)(sst + b * SS + (k4 << 2)) = v[u];
    }
    __syncthreads();
}

// Stage 32 x 128 chunk of immutable x (plain cached loads).
__device__ __forceinline__ void stage128p(float* sst, const float* g,
                                          long rowStride) {
    __syncthreads();
#pragma unroll
    for (int u = 0; u < 2; ++u) {
        int i = threadIdx.x + u * NT;
        int b = i & 31, k4 = i >> 5;
        float4 v = *(const float4*)(g + (long)b * rowStride + (k4 << 2));
        *(float4*)(sst + b * SS + (k4 << 2)) = v;
    }
    __syncthreads();
}

__device__ __forceinline__ float dotK(const float* sst,
                                      const float* __restrict__ W, int b,
                                      int K) {
    const float* s = sst + b * SS;
    float a0 = 0.f, a1 = 0.f, a2 = 0.f, a3 = 0.f;
#pragma unroll 8
    for (int k = 0; k < K; k += 4) {
        float4 h = *(const float4*)(s + k);
        float4 w = *(const float4*)(W + k);
        a0 = fmaf(w.x, h.x, a0);
        a1 = fmaf(w.y, h.y, a1);
        a2 = fmaf(w.z, h.z, a2);
        a3 = fmaf(w.w, h.w, a3);
    }
    return (a0 + a1) + (a2 + a3);
}

__global__ void bar_init(int* bar) {
    for (int i = threadIdx.x; i < 1024; i += 256) bar[i] = 0;
}

__global__ __launch_bounds__(NT, 1) void gru_fused(
    const float* __restrict__ x, const float* __restrict__ h0in,
    const float* __restrict__ Wx0, const float* __restrict__ Wh0,
    const float* __restrict__ bh0, const float* __restrict__ Wx1,
    const float* __restrict__ Wh1, const float* __restrict__ bh1,
    const float* __restrict__ Why, const float* __restrict__ bhy,
    float* __restrict__ out, float* __restrict__ ws) {
    __shared__ float sst[32 * SS];  // 33.3 KB
    const int w = blockIdx.x;
    const int tid = threadIdx.x;
    const int slot = tid >> 5;   // 0..15
    const int b = tid & 31;
    int* bar = (int*)(ws + 196608);
    int ep = 0;

    // workspace (floats): cross-WG data, coherent access only
    float* h0 = ws;             // [b*512+j]
    float* h1 = ws + 16384;
    float* xzr0 = ws + 32768;   // [b*1024+j]
    float* xg0 = ws + 65536;    // [b*512+j]
    float* z0 = ws + 81920;
    float* rh0 = ws + 98304;
    float* hzr1 = ws + 114688;  // [b*1024+j]
    float* z1 = ws + 147456;
    float* rh1 = ws + 163840;
    float* xg1 = ws + 180224;

    // ---- pre-loop: init states (all WGs) + xzr0 for t=0 ----
    {
        int i = w * NT + tid;  // 32768 = B*L*H exactly
        int bb = i >> 10, l = (i >> 9) & 1, j = i & 511;
        st_coh((l ? h1 : h0) + bb * Hq + j, h0in[i]);
        stage128p(sst, x, (long)Sq * Iq);  // x_0
        int jz = w * 16 + slot;            // 0..1023
        st_coh(xzr0 + b * 1024 + jz, dotK(sst, Wx0 + jz * Iq, b, Iq));
    }
    flagbar(bar, ++ep);

    for (int t = 0;; ++t) {
        // ==== phase A ====
        if (t == Sq) {
            // epilogue: final y + hidden-state dump
            float ay = 0.f;
            int o = w * 2 + slot;
            bool doy = slot < 2;
            for (int kb = 0; kb < Hq; kb += 256) {
                stage256(sst, h1, kb);
                if (doy) ay += dotK(sst, Why + o * Hq + kb, b, 256);
            }
            if (doy) out[((size_t)b * Sq + (Sq - 1)) * Oq + o] = ay + bhy[o];
            int i = w * NT + tid;
            int bb = i >> 10, l = (i >> 9) & 1, j = i & 511;
            out[(size_t)Bq * Sq * Oq + i] = ld_coh((l ? h1 : h0) + bb * Hq + j);
            break;
        }
        {
            // A1: zr0 (all 16 slots), over staged h0
            int j = w * 16 + slot;  // 0..1023
            const float* Wr = Wh0 + j * Hq;
            float a = 0.f;
            for (int kb = 0; kb < Hq; kb += 256) {
                stage256(sst, h0, kb);
                a += dotK(sst, Wr + kb, b, 256);
            }
            float s = sigmoidf_(ld_coh(xzr0 + b * 1024 + j) + a + bh0[j]);
            if (j < Hq)
                st_coh(z0 + b * Hq + j, s);
            else
                st_coh(rh0 + b * Hq + (j - Hq),
                       s * ld_coh(h0 + b * Hq + (j - Hq)));

            // A2: hzr1 (all slots) + y_{t-1} (slots 0-1), over staged h1
            int j2 = w * 16 + slot;
            const float* W2 = Wh1 + j2 * Hq;
            int o = w * 2 + slot;
            bool doy = slot < 2;
            float a2 = 0.f, ay = 0.f;
            for (int kb = 0; kb < Hq; kb += 256) {
                stage256(sst, h1, kb);
                a2 += dotK(sst, W2 + kb, b, 256);
                if (doy) ay += dotK(sst, Why + o * Hq + kb, b, 256);
            }
            st_coh(hzr1 + b * 1024 + j2, a2 + bh1[j2]);
            if (doy && t > 0)
                out[((size_t)b * Sq + (t - 1)) * Oq + o] = ay + bhy[o];

            // A3: xg0 (slots 0-7), over staged x_t
            stage128p(sst, x + (long)t * Iq, (long)Sq * Iq);
            if (slot < 8) {
                int j3 = w * 8 + slot;  // 0..511
                st_coh(xg0 + b * Hq + j3,
                       dotK(sst, Wx0 + (2 * Hq + j3) * Iq, b, Iq));
            }
        }
        flagbar(bar, ++ep);

        // ==== phase B: g0, h0 update (slots 0-7) ====
        {
            int j = w * 8 + slot;  // 0..511
            bool act = slot < 8;
            const float* Wr = Wh0 + (2 * Hq + j) * Hq;
            float a = 0.f;
            for (int kb = 0; kb < Hq; kb += 256) {
                stage256(sst, rh0, kb);
                if (act) a += dotK(sst, Wr + kb, b, 256);
            }
            if (act) {
                float g = tanhf(ld_coh(xg0 + b * Hq + j) + a + bh0[2 * Hq + j]);
                float zz = ld_coh(z0 + b * Hq + j);
                float h = ld_coh(h0 + b * Hq + j);
                st_coh(h0 + b * Hq + j, zz * h + (1.f - zz) * g);
            }
        }
        flagbar(bar, ++ep);

        // ==== phase C: zr1 (all slots) + xg1 (slots 0-7), over staged h0' ====
        {
            int j = w * 16 + slot;  // 0..1023
            const float* Wr = Wx1 + j * Hq;
            int j4 = w * 8 + slot;  // 0..511
            const float* W4 = Wx1 + (2 * Hq + j4) * Hq;
            bool act4 = slot < 8;
            float a = 0.f, a4 = 0.f;
            for (int kb = 0; kb < Hq; kb += 256) {
                stage256(sst, h0, kb);
                a += dotK(sst, Wr + kb, b, 256);
                if (act4) a4 += dotK(sst, W4 + kb, b, 256);
            }
            float s = sigmoidf_(a + ld_coh(hzr1 + b * 1024 + j));
            if (j < Hq)
                st_coh(z1 + b * Hq + j, s);
            else
                st_coh(rh1 + b * Hq + (j - Hq),
                       s * ld_coh(h1 + b * Hq + (j - Hq)));
            if (act4) st_coh(xg1 + b * Hq + j4, a4);
        }
        flagbar(bar, ++ep);

        // ==== phase D: g1, h1 update (slots 0-7) + xzr0 next (all slots) ====
        {
            int j = w * 8 + slot;
            bool act = slot < 8;
            const float* Wr = Wh1 + (2 * Hq + j) * Hq;
            float a = 0.f;
            for (int kb = 0; kb < Hq; kb += 256) {
                stage256(sst, rh1, kb);
                if (act) a += dotK(sst, Wr + kb, b, 256);
            }
            if (act) {
                float g = tanhf(ld_coh(xg1 + b * Hq + j) + a + bh1[2 * Hq + j]);
                float zz = ld_coh(z1 + b * Hq + j);
                float h = ld_coh(h1 + b * Hq + j);
                st_coh(h1 + b * Hq + j, zz * h + (1.f - zz) * g);
            }
            if (t + 1 < Sq) {
                stage128p(sst, x + (long)(t + 1) * Iq, (long)Sq * Iq);
                int jz = w * 16 + slot;
                st_coh(xzr0 + b * 1024 + jz,
                       dotK(sst, Wx0 + jz * Iq, b, Iq));
            }
        }
        flagbar(bar, ++ep);
    }
}

extern "C" void kernel_launch(void* const* d_in, const int* in_sizes, int n_in,
                              void* d_out, int out_size, void* d_ws,
                              size_t ws_size, hipStream_t stream) {
    const float* x = (const float*)d_in[0];
    const float* h0in = (const float*)d_in[1];
    const float* Wx0 = (const float*)d_in[2];
    const float* Wh0 = (const float*)d_in[3];
    const float* bh0 = (const float*)d_in[4];
    const float* Wx1 = (const float*)d_in[5];
    const float* Wh1 = (const float*)d_in[6];
    const float* bh1 = (const float*)d_in[7];
    const float* Why = (const float*)d_in[8];
    const float* bhy = (const float*)d_in[9];
    float* out = (float*)d_out;
    float* ws = (float*)d_ws;
    int* bar = (int*)(ws + 196608);

    bar_init<<<1, 256, 0, stream>>>(bar);
    gru_fused<<<dim3(NWG), dim3(NT), 0, stream>>>(x, h0in, Wx0, Wh0, bh0, Wx1,
                                                  Wh1, bh1, Why, bhy, out, ws);
}

// Round 7
// 143733.813 us; speedup vs baseline: 1.4475x; 1.4475x over previous
//
#include <hip/hip_runtime.h>

#define Sq 2048
#define Iq 128
#define Hq 512
#define Oq 128
#define NWG 64
#define NT 256
#define SS 260  // LDS row stride (floats): 16B aligned, 4-way bank alias only
#define HIDOFF 8388608  // 32*2048*128, start of hidden_state in out

typedef float v4f __attribute__((ext_vector_type(4)));

__device__ __forceinline__ float sigmoidf_(float v) {
    return 1.0f / (1.0f + __expf(-v));
}

// ---- device-coherent (sc0 sc1) primitives: always valid, no fences ----
__device__ __forceinline__ float ld1c(const float* p) {
    float r;
    asm volatile("global_load_dword %0, %1, off sc0 sc1\n\ts_waitcnt vmcnt(0)"
                 : "=v"(r) : "v"(p) : "memory");
    return r;
}
__device__ __forceinline__ int ld1ci(const int* p) {
    int r;
    asm volatile("global_load_dword %0, %1, off sc0 sc1\n\ts_waitcnt vmcnt(0)"
                 : "=v"(r) : "v"(p) : "memory");
    return r;
}
__device__ __forceinline__ void st1c(float* p, float v) {
    asm volatile("global_store_dword %0, %1, off sc0 sc1" ::"v"(p), "v"(v)
                 : "memory");
}
__device__ __forceinline__ void st1ci(int* p, int v) {
    asm volatile("global_store_dword %0, %1, off sc0 sc1" ::"v"(p), "v"(v)
                 : "memory");
}
// 8 contiguous dwordx4 from one pointer — one round trip
__device__ __forceinline__ void ld8c(v4f* v, const float* p) {
    asm volatile(
        "global_load_dwordx4 %0, %8, off sc0 sc1\n\t"
        "global_load_dwordx4 %1, %8, off offset:16 sc0 sc1\n\t"
        "global_load_dwordx4 %2, %8, off offset:32 sc0 sc1\n\t"
        "global_load_dwordx4 %3, %8, off offset:48 sc0 sc1\n\t"
        "global_load_dwordx4 %4, %8, off offset:64 sc0 sc1\n\t"
        "global_load_dwordx4 %5, %8, off offset:80 sc0 sc1\n\t"
        "global_load_dwordx4 %6, %8, off offset:96 sc0 sc1\n\t"
        "global_load_dwordx4 %7, %8, off offset:112 sc0 sc1\n\t"
        "s_waitcnt vmcnt(0)"
        : "=&v"(v[0]), "=&v"(v[1]), "=&v"(v[2]), "=&v"(v[3]), "=&v"(v[4]),
          "=&v"(v[5]), "=&v"(v[6]), "=&v"(v[7])
        : "v"(p) : "memory");
}
// 8+8 dwordx4 from two pointers — one round trip
__device__ __forceinline__ void ld8x2c(v4f* a, v4f* c, const float* p0,
                                       const float* p1) {
    asm volatile(
        "global_load_dwordx4 %0, %16, off sc0 sc1\n\t"
        "global_load_dwordx4 %1, %16, off offset:16 sc0 sc1\n\t"
        "global_load_dwordx4 %2, %16, off offset:32 sc0 sc1\n\t"
        "global_load_dwordx4 %3, %16, off offset:48 sc0 sc1\n\t"
        "global_load_dwordx4 %4, %16, off offset:64 sc0 sc1\n\t"
        "global_load_dwordx4 %5, %16, off offset:80 sc0 sc1\n\t"
        "global_load_dwordx4 %6, %16, off offset:96 sc0 sc1\n\t"
        "global_load_dwordx4 %7, %16, off offset:112 sc0 sc1\n\t"
        "global_load_dwordx4 %8, %17, off sc0 sc1\n\t"
        "global_load_dwordx4 %9, %17, off offset:16 sc0 sc1\n\t"
        "global_load_dwordx4 %10, %17, off offset:32 sc0 sc1\n\t"
        "global_load_dwordx4 %11, %17, off offset:48 sc0 sc1\n\t"
        "global_load_dwordx4 %12, %17, off offset:64 sc0 sc1\n\t"
        "global_load_dwordx4 %13, %17, off offset:80 sc0 sc1\n\t"
        "global_load_dwordx4 %14, %17, off offset:96 sc0 sc1\n\t"
        "global_load_dwordx4 %15, %17, off offset:112 sc0 sc1\n\t"
        "s_waitcnt vmcnt(0)"
        : "=&v"(a[0]), "=&v"(a[1]), "=&v"(a[2]), "=&v"(a[3]), "=&v"(a[4]),
          "=&v"(a[5]), "=&v"(a[6]), "=&v"(a[7]), "=&v"(c[0]), "=&v"(c[1]),
          "=&v"(c[2]), "=&v"(c[3]), "=&v"(c[4]), "=&v"(c[5]), "=&v"(c[6]),
          "=&v"(c[7])
        : "v"(p0), "v"(p1) : "memory");
}
// 2+2 dwordx4 from two pointers — one round trip (per-row gathers)
__device__ __forceinline__ void ld2x2c(v4f* v, const float* p0,
                                       const float* p1) {
    asm volatile(
        "global_load_dwordx4 %0, %4, off sc0 sc1\n\t"
        "global_load_dwordx4 %1, %4, off offset:16 sc0 sc1\n\t"
        "global_load_dwordx4 %2, %5, off sc0 sc1\n\t"
        "global_load_dwordx4 %3, %5, off offset:16 sc0 sc1\n\t"
        "s_waitcnt vmcnt(0)"
        : "=&v"(v[0]), "=&v"(v[1]), "=&v"(v[2]), "=&v"(v[3])
        : "v"(p0), "v"(p1) : "memory");
}
__device__ __forceinline__ void ld2x3c(v4f* v, const float* p0,
                                       const float* p1, const float* p2) {
    asm volatile(
        "global_load_dwordx4 %0, %6, off sc0 sc1\n\t"
        "global_load_dwordx4 %1, %6, off offset:16 sc0 sc1\n\t"
        "global_load_dwordx4 %2, %7, off sc0 sc1\n\t"
        "global_load_dwordx4 %3, %7, off offset:16 sc0 sc1\n\t"
        "global_load_dwordx4 %4, %8, off sc0 sc1\n\t"
        "global_load_dwordx4 %5, %8, off offset:16 sc0 sc1\n\t"
        "s_waitcnt vmcnt(0)"
        : "=&v"(v[0]), "=&v"(v[1]), "=&v"(v[2]), "=&v"(v[3]), "=&v"(v[4]),
          "=&v"(v[5])
        : "v"(p0), "v"(p1), "v"(p2) : "memory");
}

// ---- store/scan barrier: 64 WGs, one cache line per flag, monotone gens ----
__device__ __forceinline__ void gbar(int* flags, int ep) {
    asm volatile("s_waitcnt vmcnt(0) lgkmcnt(0)" ::: "memory");
    __syncthreads();
    if (threadIdx.x == 0) st1ci(flags + (blockIdx.x << 5), ep);
    if (threadIdx.x < 64) {
        for (;;) {
            int f = ld1ci(flags + (threadIdx.x << 5));
            if (__all(f >= ep)) break;
            __builtin_amdgcn_s_sleep(1);
        }
    }
    __syncthreads();
}

// ---- LDS staging: 32 x 256 floats -> sst[b*SS + k] ----
__device__ __forceinline__ void stageC(float* sst, const float* src, int k0) {
    __syncthreads();
    int bb = threadIdx.x & 31, part = threadIdx.x >> 5;
    v4f v[8];
    ld8c(v, src + bb * Hq + k0 + part * 32);
    v4f* d = (v4f*)(sst + bb * SS + part * 32);
#pragma unroll
    for (int i = 0; i < 8; ++i) d[i] = v[i];
    __syncthreads();
}
// rh0 on the fly: sigmoid(pre_r) * h0  (pre_r = hzr0f rows 512..1023)
__device__ __forceinline__ void stageRH(float* sst, const float* h0c,
                                        const float* hzr0f, int k0) {
    __syncthreads();
    int bb = threadIdx.x & 31, part = threadIdx.x >> 5;
    int off = k0 + part * 32;
    v4f hv[8], pv[8];
    ld8x2c(hv, pv, h0c + bb * Hq + off, hzr0f + bb * 1024 + Hq + off);
    v4f* d = (v4f*)(sst + bb * SS + part * 32);
#pragma unroll
    for (int i = 0; i < 8; ++i) {
        v4f s;
        s.x = sigmoidf_(pv[i].x) * hv[i].x;
        s.y = sigmoidf_(pv[i].y) * hv[i].y;
        s.z = sigmoidf_(pv[i].z) * hv[i].z;
        s.w = sigmoidf_(pv[i].w) * hv[i].w;
        d[i] = s;
    }
    __syncthreads();
}
// plain cached stage (immutable inputs), arbitrary row stride
__device__ __forceinline__ void stageP(float* sst, const float* src,
                                       long stride, int k0) {
    __syncthreads();
    int bb = threadIdx.x & 31, part = threadIdx.x >> 5;
    const v4f* p = (const v4f*)(src + bb * stride + k0 + part * 32);
    v4f* d = (v4f*)(sst + bb * SS + part * 32);
#pragma unroll
    for (int i = 0; i < 8; ++i) d[i] = p[i];
    __syncthreads();
}
// x_t: 32 x 128 floats, plain cached
__device__ __forceinline__ void stageX(float* sst, const float* x, int t) {
    __syncthreads();
    int bb = threadIdx.x & 31, part = threadIdx.x >> 5;  // 8 parts x 16 floats
    const v4f* p = (const v4f*)(x + ((long)bb * Sq + t) * Iq + part * 16);
    v4f* d = (v4f*)(sst + bb * SS + part * 16);
    d[0] = p[0]; d[1] = p[1]; d[2] = p[2]; d[3] = p[3];
    __syncthreads();
}

// ---- R weight rows vs staged column b ----
template <int R>
__device__ __forceinline__ void dotRp(float* acc, const float* sst, int b,
                                      const float* const* wp, int k0, int K) {
    const float* sp = sst + b * SS;
#pragma unroll 8
    for (int k = 0; k < K; k += 4) {
        v4f h = *(const v4f*)(sp + k);
#pragma unroll
        for (int j = 0; j < R; ++j) {
            v4f w = *(const v4f*)(wp[j] + k0 + k);
            acc[j] = fmaf(w.x, h.x, acc[j]);
            acc[j] = fmaf(w.y, h.y, acc[j]);
            acc[j] = fmaf(w.z, h.z, acc[j]);
            acc[j] = fmaf(w.w, h.w, acc[j]);
        }
    }
}

__global__ void bar_init(int* bar) {
    for (int i = threadIdx.x; i < 4096; i += 256) bar[i] = 0;
}

__global__ __launch_bounds__(NT, 1) void gru_fused(
    const float* __restrict__ x, const float* __restrict__ h0in,
    const float* __restrict__ Wx0, const float* __restrict__ Wh0,
    const float* __restrict__ bh0, const float* __restrict__ Wx1,
    const float* __restrict__ Wh1, const float* __restrict__ bh1,
    const float* __restrict__ Why, const float* __restrict__ bhy,
    float* __restrict__ out, float* __restrict__ ws) {
    __shared__ float sst[32 * SS];
    const int rank = blockIdx.x;
    const int tid = threadIdx.x;
    const int slot = tid >> 5, b = tid & 31;

    // ws layout (floats); all cross-WG data accessed sc0sc1 only
    float* h0b0 = ws;            // 16384 [b*512+j]
    float* h0b1 = ws + 16384;
    float* h1 = ws + 32768;
    float* hzr0f = ws + 49152;   // 32768 [b*1024+row] full z,r pre-acts (x+h+bias)
    float* hzr1 = ws + 81920;    // 32768 [b*1024+row] h-side z,r pre-acts (+bias)
    float* z1 = ws + 114688;     // 16384
    float* rh1 = ws + 131072;    // 16384
    float* xg1 = ws + 147456;    // 16384
    int* flags = (int*)(ws + 163840);
    int ep = 0;

    // ---- prologue: init states; hzr0f(0) from h0in(l=0) + x(0) ----
    {
#pragma unroll
        for (int u = 0; u < 2; ++u) {
            int i = rank * 512 + u * NT + tid;  // 64*512 = 32768 = B*L*H
            int bb = i >> 10, l = (i >> 9) & 1, j = i & 511;
            st1c((l ? h1 : h0b0) + bb * Hq + j, h0in[i]);
        }
        int r0 = rank * 16 + slot * 2;  // 1024 rows exact
        float acc[2] = {0.f, 0.f};
        const float* wp[2] = {Wh0 + r0 * Hq, Wh0 + (r0 + 1) * Hq};
        const float* wpx[2] = {Wx0 + r0 * Iq, Wx0 + (r0 + 1) * Iq};
        stageP(sst, h0in, 1024, 0);  // h0 init lives at l=0, row stride 1024
        dotRp<2>(acc, sst, b, wp, 0, 256);
        stageP(sst, h0in, 1024, 256);
        dotRp<2>(acc, sst, b, wp, 256, 256);
        stageX(sst, x, 0);
        dotRp<2>(acc, sst, b, wpx, 0, Iq);
#pragma unroll
        for (int j = 0; j < 2; ++j)
            st1c(hzr0f + b * 1024 + r0 + j, acc[j] + bh0[r0 + j]);
    }
    gbar(flags, ++ep);

    for (int t = 0; t < Sq; ++t) {
        float* h0c = (t & 1) ? h0b1 : h0b0;
        float* h0n = (t & 1) ? h0b0 : h0b1;

        // ==== P1: [0..22] g0 + h0 update | [23..63] y(t-1) + hzr1 ====
        if (rank < 23) {
            int lo = (rank << 9) / 23, hi = ((rank + 1) << 9) / 23;
            int r0 = lo + slot * 3;
            float acc[3] = {0.f, 0.f, 0.f};
            const float* wp[3];
            const float* wpx[3];
#pragma unroll
            for (int j = 0; j < 3; ++j) {
                int r = r0 + j; if (r >= hi) r = hi - 1;
                wp[j] = Wh0 + (1024 + r) * Hq;
                wpx[j] = Wx0 + (1024 + r) * Iq;
            }
            stageRH(sst, h0c, hzr0f, 0);
            dotRp<3>(acc, sst, b, wp, 0, 256);
            stageRH(sst, h0c, hzr0f, 256);
            dotRp<3>(acc, sst, b, wp, 256, 256);
            stageX(sst, x, t);
            dotRp<3>(acc, sst, b, wpx, 0, Iq);
            v4f g4[4];
            ld2x2c(g4, hzr0f + b * 1024 + r0, h0c + b * Hq + r0);
            const float* zpre = (const float*)g4;
            const float* hov = (const float*)(g4 + 2);
#pragma unroll
            for (int j = 0; j < 3; ++j) {
                int r = r0 + j;
                if (r < hi) {
                    float z = sigmoidf_(zpre[j]);
                    float g = tanhf(acc[j] + bh0[1024 + r]);
                    st1c(h0n + b * Hq + r, z * hov[j] + (1.f - z) * g);
                }
            }
        } else {
            int wb = rank - 23;  // 0..40, rows 1152 = y(128) + hzr1(1024)
            int lo = (wb * 1152) / 41, hi = ((wb + 1) * 1152) / 41;
            int r0 = lo + slot * 4;
            float acc[4] = {0.f, 0.f, 0.f, 0.f};
            const float* wp[4];
#pragma unroll
            for (int j = 0; j < 4; ++j) {
                int r = r0 + j; if (r >= hi) r = hi - 1;
                wp[j] = (r < Oq) ? (Why + r * Hq) : (Wh1 + (r - Oq) * Hq);
            }
            stageC(sst, h1, 0);
            dotRp<4>(acc, sst, b, wp, 0, 256);
            stageC(sst, h1, 256);
            dotRp<4>(acc, sst, b, wp, 256, 256);
#pragma unroll
            for (int j = 0; j < 4; ++j) {
                int r = r0 + j;
                if (r < hi) {
                    if (r < Oq) {
                        if (t > 0)
                            out[((size_t)b * Sq + (t - 1)) * Oq + r] =
                                acc[j] + bhy[r];
                    } else {
                        st1c(hzr1 + b * 1024 + (r - Oq), acc[j] + bh1[r - Oq]);
                    }
                }
            }
        }
        gbar(flags, ++ep);

        // ==== P2: all WGs — zrg1 = Wx1 (1536 rows) over h0' ====
        {
            int zb = rank * 24 + slot * 3;  // exact cover 0..1535
            float acc[3] = {0.f, 0.f, 0.f};
            const float* wp[3];
#pragma unroll
            for (int j = 0; j < 3; ++j) wp[j] = Wx1 + (zb + j) * Hq;
            stageC(sst, h0n, 0);
            dotRp<3>(acc, sst, b, wp, 0, 256);
            stageC(sst, h0n, 256);
            dotRp<3>(acc, sst, b, wp, 256, 256);
            int hb = zb - Hq;
            int hbs = hb > 0 ? hb : 0;
            const float* php =
                (zb < 1024) ? (hzr1 + b * 1024 + zb) : (hzr1 + b * 1024);
            v4f g4[4];
            ld2x2c(g4, php, h1 + b * Hq + hbs);
            const float* hzv = (const float*)g4;
            const float* h1v = (const float*)(g4 + 2);
#pragma unroll
            for (int j = 0; j < 3; ++j) {
                int row = zb + j;
                if (row < Hq) {
                    st1c(z1 + b * Hq + row, sigmoidf_(acc[j] + hzv[j]));
                } else if (row < 1024) {
                    float r = sigmoidf_(acc[j] + hzv[j]);
                    float hv = (hb >= 0) ? h1v[j]
                                         : ld1c(h1 + b * Hq + (row - Hq));
                    st1c(rh1 + b * Hq + (row - Hq), r * hv);
                } else {
                    st1c(xg1 + b * Hq + (row - 1024), acc[j]);
                }
            }
        }
        gbar(flags, ++ep);

        // ==== P3: [0..17] g1 + h1 update | [18..63] zr0(t+1) pre-acts ====
        if (rank < 18) {
            int lo = (rank << 9) / 18, hi = ((rank + 1) << 9) / 18;
            int r0 = lo + slot * 4;
            float acc[4] = {0.f, 0.f, 0.f, 0.f};
            const float* wp[4];
#pragma unroll
            for (int j = 0; j < 4; ++j) {
                int r = r0 + j; if (r >= hi) r = hi - 1;
                wp[j] = Wh1 + (1024 + r) * Hq;
            }
            stageC(sst, rh1, 0);
            dotRp<4>(acc, sst, b, wp, 0, 256);
            stageC(sst, rh1, 256);
            dotRp<4>(acc, sst, b, wp, 256, 256);
            v4f g6[6];
            ld2x3c(g6, xg1 + b * Hq + r0, z1 + b * Hq + r0, h1 + b * Hq + r0);
            const float* xgv = (const float*)g6;
            const float* zvv = (const float*)(g6 + 2);
            const float* hvv = (const float*)(g6 + 4);
#pragma unroll
            for (int j = 0; j < 4; ++j) {
                int r = r0 + j;
                if (r < hi) {
                    float g = tanhf(acc[j] + xgv[j] + bh1[1024 + r]);
                    float z = zvv[j];
                    st1c(h1 + b * Hq + r, z * hvv[j] + (1.f - z) * g);
                }
            }
        } else {
            int rd = rank - 18;  // 0..45, rows 1024
            int lo = (rd << 10) / 46, hi = ((rd + 1) << 10) / 46;
            int r0 = lo + slot * 3;
            float acc[3] = {0.f, 0.f, 0.f};
            const float* wp[3];
            const float* wpx[3];
#pragma unroll
            for (int j = 0; j < 3; ++j) {
                int r = r0 + j; if (r >= hi) r = hi - 1;
                wp[j] = Wh0 + r * Hq;
                wpx[j] = Wx0 + r * Iq;
            }
            stageC(sst, h0n, 0);
            dotRp<3>(acc, sst, b, wp, 0, 256);
            stageC(sst, h0n, 256);
            dotRp<3>(acc, sst, b, wp, 256, 256);
            if (t + 1 < Sq) {
                stageX(sst, x, t + 1);
                dotRp<3>(acc, sst, b, wpx, 0, Iq);
#pragma unroll
                for (int j = 0; j < 3; ++j) {
                    int r = r0 + j;
                    if (r < hi)
                        st1c(hzr0f + b * 1024 + r, acc[j] + bh0[r]);
                }
            }
        }
        gbar(flags, ++ep);
    }

    // ==== epilogue: y(2047) on ranks 0..15; hidden dump on 16..63 ====
    if (rank < 16) {
        int r = rank * 8 + slot;  // 128 rows exact
        float acc1 = 0.f;
        const float* wp0 = Why + r * Hq;
        stageC(sst, h1, 0);
        dotRp<1>(&acc1, sst, b, &wp0, 0, 256);
        stageC(sst, h1, 256);
        dotRp<1>(&acc1, sst, b, &wp0, 256, 256);
        out[((size_t)b * Sq + (Sq - 1)) * Oq + r] = acc1 + bhy[r];
    } else {
        // final h0 is in h0b0 (t=2047 odd -> h0n = h0b0)
        for (int i = (rank - 16) * NT + tid; i < 32768; i += 48 * NT) {
            int bb = i >> 10, l = (i >> 9) & 1, j = i & 511;
            out[(size_t)HIDOFF + i] = ld1c((l ? h1 : h0b0) + bb * Hq + j);
        }
    }
}

extern "C" void kernel_launch(void* const* d_in, const int* in_sizes, int n_in,
                              void* d_out, int out_size, void* d_ws,
                              size_t ws_size, hipStream_t stream) {
    const float* x = (const float*)d_in[0];
    const float* h0in = (const float*)d_in[1];
    const float* Wx0 = (const float*)d_in[2];
    const float* Wh0 = (const float*)d_in[3];
    const float* bh0 = (const float*)d_in[4];
    const float* Wx1 = (const float*)d_in[5];
    const float* Wh1 = (const float*)d_in[6];
    const float* bh1 = (const float*)d_in[7];
    const float* Why = (const float*)d_in[8];
    const float* bhy = (const float*)d_in[9];
    float* out = (float*)d_out;
    float* ws = (float*)d_ws;
    int* barp = (int*)(ws + 163840);

    bar_init<<<1, 256, 0, stream>>>(barp);
    gru_fused<<<dim3(NWG), dim3(NT), 0, stream>>>(x, h0in, Wx0, Wh0, bh0, Wx1,
                                                  Wh1, bh1, Why, bhy, out, ws);
}